// Round 2
// baseline (1024.968 us; speedup 1.0000x reference)
//
#include <hip/hip_runtime.h>
#include <hip/hip_bf16.h>
#include <math.h>

#define B_  64
#define N_  325
#define T_  24
#define F_  64
#define H_  64
#define E_  2600
#define G_  (B_ * T_)
#define BLK 512
#define HS  66   // h_s row stride in bf16 units (132 B -> bank step 33, conflict-free)

// ---------------- K0a: per-dst counts -> exclusive offsets ----------------
__global__ __launch_bounds__(512) void k_offsets(const int* __restrict__ ei,
                                                 int* __restrict__ csr_off) {
  __shared__ int cnt[N_];
  const int tid = threadIdx.x;
  for (int i = tid; i < N_; i += BLK) cnt[i] = 0;
  __syncthreads();
  for (int e = tid; e < E_; e += BLK) atomicAdd(&cnt[ei[E_ + e]], 1);
  __syncthreads();
  if (tid <= N_) {
    int off = 0;
    for (int m = 0; m < N_; ++m) off += (m < tid) ? cnt[m] : 0;  // uniform m -> LDS broadcast
    csr_off[tid] = off;
  }
}

// ---------------- K0b: stable scatter of src ids by dst (deterministic) ----------------
__global__ __launch_bounds__(64) void k_scatter(const int* __restrict__ ei,
                                                const int* __restrict__ csr_off,
                                                int* __restrict__ csr_src) {
  __shared__ int dsts[E_];
  const int tid = threadIdx.x;
  for (int i = tid; i < E_; i += 64) dsts[i] = ei[E_ + i];
  __syncthreads();
  const int e = blockIdx.x * 64 + tid;
  if (e >= E_) return;
  const int myd = dsts[e];
  int rank = 0;
#pragma unroll 4
  for (int k = 0; k < e; ++k) rank += (dsts[k] == myd) ? 1 : 0;
  csr_src[csr_off[myd] + rank] = ei[e];  // src id, stable original-edge order
}

__device__ __forceinline__ float bflo(unsigned u) { return __uint_as_float(u << 16); }
__device__ __forceinline__ float bfhi(unsigned u) { return __uint_as_float(u & 0xffff0000u); }

// ---------------- main fused kernel: one block per graph, 2 blocks/CU ----------------
__global__ __launch_bounds__(512, 4) void k_gat(
    const float* __restrict__ x, const int* __restrict__ csr_off_g,
    const int* __restrict__ csr_src_g, const float* __restrict__ W,
    const float* __restrict__ att_src, const float* __restrict__ att_dst,
    const float* __restrict__ bias, float* __restrict__ out) {
  __shared__ unsigned short h_s[N_][HS];   // 42900 B, bf16
  __shared__ float alpha_s[E_];            // 10400 B (unnormalized exp)
  __shared__ int   csrc_s[E_];             // 10400 B
  __shared__ int   coff_s[N_ + 1];         //  1304 B
  __shared__ float as_s[N_], ad_s[N_], den_s[N_];  // 3900 B
  __shared__ __align__(8) float atts_s[H_], attd_s[H_];  // 512 B   total ~68 KB

  const int g    = blockIdx.x;      // graph id = b*T + t
  const int bb   = g / T_;
  const int tt   = g % T_;
  const int tid  = threadIdx.x;
  const int lane = tid & 63;        // = output channel h in GEMM
  const int wv   = tid >> 6;        // wave 0..7

  // stage CSR + att vectors
  for (int i = tid; i < E_; i += BLK) csrc_s[i] = csr_src_g[i];
  for (int i = tid; i <= N_; i += BLK) coff_s[i] = csr_off_g[i];
  if (tid < H_) { atts_s[tid] = att_src[tid]; attd_s[tid] = att_dst[tid]; }

  // per-lane W row (lane = h channel) in registers
  float wreg[F_];
  {
    const float4* w4 = (const float4*)(W + lane * F_);
#pragma unroll
    for (int i = 0; i < 16; ++i) {
      float4 v = w4[i];
      wreg[4 * i + 0] = v.x; wreg[4 * i + 1] = v.y;
      wreg[4 * i + 2] = v.z; wreg[4 * i + 3] = v.w;
    }
  }

  // ---------- Phase 1: h = x @ W^T (bf16 into LDS); x rows broadcast from global ----------
  const float* xg = x + ((size_t)bb * N_ * T_ + tt) * F_;
  for (int r = wv; r < N_; r += 8) {
    const float4* xr4 = (const float4*)(xg + (size_t)r * T_ * F_);
    float a0 = 0.f, a1 = 0.f, a2 = 0.f, a3 = 0.f;
#pragma unroll
    for (int i = 0; i < 16; ++i) {
      float4 v = xr4[i];                      // same addr across lanes -> broadcast
      a0 += v.x * wreg[4 * i + 0];
      a1 += v.y * wreg[4 * i + 1];
      a2 += v.z * wreg[4 * i + 2];
      a3 += v.w * wreg[4 * i + 3];
    }
    const float acc = (a0 + a1) + (a2 + a3);
    __hip_bfloat16 hb = __float2bfloat16(acc);
    h_s[r][lane] = *(unsigned short*)&hb;
  }
  __syncthreads();

  // ---------- Phase 2a: per-node attention logits (thread n) ----------
  for (int n = tid; n < N_; n += BLK) {
    const unsigned* hr = (const unsigned*)&h_s[n][0];
    const float2* at2 = (const float2*)atts_s;
    const float2* ad2 = (const float2*)attd_s;
    float as = 0.f, ad = 0.f;
#pragma unroll
    for (int i = 0; i < 32; ++i) {
      unsigned hp = hr[i];
      float h0 = bflo(hp), h1 = bfhi(hp);
      float2 s2 = at2[i], d2 = ad2[i];
      as += h0 * s2.x + h1 * s2.y;
      ad += h0 * d2.x + h1 * d2.y;
    }
    as_s[n] = as; ad_s[n] = ad;
  }
  __syncthreads();

  // ---------- Phase 2b: per-dst segment softmax (thread n) ----------
  for (int n = tid; n < N_; n += BLK) {
    const int beg = coff_s[n], end = coff_s[n + 1];
    const float adn = ad_s[n];
    float mx = -1e30f;
    for (int p = beg; p < end; ++p) {
      float e = as_s[csrc_s[p]] + adn;
      e = fmaxf(e, 0.2f * e);                 // leaky_relu
      alpha_s[p] = e;
      mx = fmaxf(mx, e);
    }
    float den = 0.f;
    for (int p = beg; p < end; ++p) {
      float ex = __expf(alpha_s[p] - mx);
      alpha_s[p] = ex;                        // unnormalized
      den += ex;
    }
    den_s[n] = (end > beg) ? den : 1.0f;
  }
  __syncthreads();

  // ---------- Phase 3: aggregation + GELU (wave per dst, 2 edges/iter) ----------
  const int k    = lane & 31;                 // channel pair index
  const int half = lane >> 5;                 // which edge of the pair
  const float2 bias2 = *(const float2*)(bias + 2 * k);
  for (int n = wv; n < N_; n += 8) {
    const int beg = coff_s[n], end = coff_s[n + 1];
    float ax = 0.f, ay = 0.f;
    for (int p = beg; p < end; p += 2) {
      const int idx = p + half;
      const int ic  = (idx < end) ? idx : p;  // clamp (p < end guaranteed)
      float a = alpha_s[ic];
      a = (idx < end) ? a : 0.f;
      const int s = csrc_s[ic];
      unsigned hp = *(const unsigned*)&h_s[s][2 * k];
      ax += a * bflo(hp);
      ay += a * bfhi(hp);
    }
    ax += __shfl_xor(ax, 32, 64);
    ay += __shfl_xor(ay, 32, 64);
    const float r = 1.0f / den_s[n];
    float v0 = ax * r + bias2.x;
    float v1 = ay * r + bias2.y;
    v0 = 0.5f * v0 * (1.f + erff(v0 * 0.70710678118f));
    v1 = 0.5f * v1 * (1.f + erff(v1 * 0.70710678118f));
    if (half == 0)
      *(float2*)&out[((size_t)g * N_ + n) * H_ + 2 * k] = make_float2(v0, v1);
  }
}

extern "C" void kernel_launch(void* const* d_in, const int* in_sizes, int n_in,
                              void* d_out, int out_size, void* d_ws, size_t ws_size,
                              hipStream_t stream) {
  (void)in_sizes; (void)n_in; (void)out_size; (void)ws_size;
  const float* x       = (const float*)d_in[0];
  const int*   ei      = (const int*)d_in[1];
  const float* W       = (const float*)d_in[2];
  const float* att_src = (const float*)d_in[3];
  const float* att_dst = (const float*)d_in[4];
  const float* bias    = (const float*)d_in[5];
  float* out = (float*)d_out;
  int* csr_off = (int*)d_ws;              // N_+1 ints
  int* csr_src = csr_off + (N_ + 1);      // E_ ints

  k_offsets<<<1, BLK, 0, stream>>>(ei, csr_off);
  k_scatter<<<(E_ + 63) / 64, 64, 0, stream>>>(ei, csr_off, csr_src);
  k_gat<<<G_, BLK, 0, stream>>>(x, csr_off, csr_src, W, att_src, att_dst, bias, out);
}

// Round 3
// 279.593 us; speedup vs baseline: 3.6659x; 3.6659x over previous
//
#include <hip/hip_runtime.h>
#include <hip/hip_bf16.h>
#include <math.h>

#define B_  64
#define N_  325
#define T_  24
#define F_  64
#define H_  64
#define E_  2600
#define G_  (B_ * T_)
#define BLK 512
#define HS  66   // h_s row stride in bf16 units (132 B -> bank step 33, conflict-free)
#define CR  32   // x chunk rows
#define XP  68   // x_s row stride in floats (272 B, 16B-aligned)

// ---------------- K0a: per-dst counts -> exclusive offsets ----------------
__global__ __launch_bounds__(512) void k_offsets(const int* __restrict__ ei,
                                                 int* __restrict__ csr_off) {
  __shared__ int cnt[N_];
  const int tid = threadIdx.x;
  for (int i = tid; i < N_; i += BLK) cnt[i] = 0;
  __syncthreads();
  for (int e = tid; e < E_; e += BLK) atomicAdd(&cnt[ei[E_ + e]], 1);
  __syncthreads();
  if (tid <= N_) {
    int off = 0;
    for (int m = 0; m < N_; ++m) off += (m < tid) ? cnt[m] : 0;  // uniform m -> LDS broadcast
    csr_off[tid] = off;
  }
}

// ---------------- K0b: stable scatter of src ids by dst (deterministic) ----------------
__global__ __launch_bounds__(64) void k_scatter(const int* __restrict__ ei,
                                                const int* __restrict__ csr_off,
                                                int* __restrict__ csr_src) {
  __shared__ int dsts[E_];
  const int tid = threadIdx.x;
  for (int i = tid; i < E_; i += 64) dsts[i] = ei[E_ + i];
  __syncthreads();
  const int e = blockIdx.x * 64 + tid;
  if (e >= E_) return;
  const int myd = dsts[e];
  int rank = 0;
#pragma unroll 4
  for (int k = 0; k < e; ++k) rank += (dsts[k] == myd) ? 1 : 0;
  csr_src[csr_off[myd] + rank] = ei[e];  // src id, stable original-edge order
}

__device__ __forceinline__ float bflo(unsigned u) { return __uint_as_float(u << 16); }
__device__ __forceinline__ float bfhi(unsigned u) { return __uint_as_float(u & 0xffff0000u); }

// ---------------- main fused kernel: one block per graph, 2 blocks/CU ----------------
__global__ __launch_bounds__(512, 4) void k_gat(
    const float* __restrict__ x, const int* __restrict__ csr_off_g,
    const int* __restrict__ csr_src_g, const float* __restrict__ W,
    const float* __restrict__ att_src, const float* __restrict__ att_dst,
    const float* __restrict__ bias, float* __restrict__ out) {
  __shared__ unsigned short h_s[N_][HS];            // 42900 B, bf16
  __shared__ __align__(16) float x_s[CR][XP];       //  8704 B
  __shared__ float alpha_s[E_];                     // 10400 B (unnormalized exp)
  __shared__ unsigned short csrc_s[E_];             //  5200 B (src ids < 325)
  __shared__ int   coff_s[N_ + 1];                  //  1304 B
  __shared__ float as_s[N_], ad_s[N_], den_s[N_];   //  3900 B
  __shared__ __align__(8) float atts_s[H_], attd_s[H_];  // 512 B   total ~72.9 KB

  const int g    = blockIdx.x;      // graph id = b*T + t
  const int bb   = g / T_;
  const int tt   = g % T_;
  const int tid  = threadIdx.x;
  const int lane = tid & 63;        // = output channel h in GEMM / phase 3
  const int wv   = tid >> 6;        // wave 0..7

  // stage CSR + att vectors (used only after phase-1's final sync)
  for (int i = tid; i < E_; i += BLK) csrc_s[i] = (unsigned short)csr_src_g[i];
  for (int i = tid; i <= N_; i += BLK) coff_s[i] = csr_off_g[i];
  if (tid < H_) { atts_s[tid] = att_src[tid]; attd_s[tid] = att_dst[tid]; }

  // per-lane W row (lane = h channel) in registers
  float wreg[F_];
  {
    const float4* w4 = (const float4*)(W + lane * F_);
#pragma unroll
    for (int i = 0; i < 16; ++i) {
      float4 v = w4[i];
      wreg[4 * i + 0] = v.x; wreg[4 * i + 1] = v.y;
      wreg[4 * i + 2] = v.z; wreg[4 * i + 3] = v.w;
    }
  }

  // ---------- Phase 1: h = x @ W^T (bf16 into LDS), chunked coalesced staging ----------
  const float* xg = x + ((size_t)bb * N_ * T_ + tt) * F_;
  for (int n0 = 0; n0 < N_; n0 += CR) {
    const int C = (N_ - n0 < CR) ? (N_ - n0) : CR;
    __syncthreads();  // previous chunk's GEMM done before overwriting x_s
    // coalesced stage: 16 float4 per row; 16 consecutive lanes cover one 256B row
    for (int i = tid; i < C * 16; i += BLK) {
      const int r = i >> 4, f4 = i & 15;
      float4 v = *(const float4*)(xg + (size_t)(n0 + r) * T_ * F_ + f4 * 4);
      *(float4*)(&x_s[r][f4 * 4]) = v;
    }
    __syncthreads();
    // wave-per-row GEMM: lane=h, x broadcast from LDS, W in regs
    for (int r = wv; r < C; r += 8) {
      const float4* xr4 = (const float4*)(&x_s[r][0]);
      float a0 = 0.f, a1 = 0.f, a2 = 0.f, a3 = 0.f;
#pragma unroll
      for (int i = 0; i < 16; ++i) {
        float4 v = xr4[i];                  // same addr across lanes -> LDS broadcast
        a0 += v.x * wreg[4 * i + 0];
        a1 += v.y * wreg[4 * i + 1];
        a2 += v.z * wreg[4 * i + 2];
        a3 += v.w * wreg[4 * i + 3];
      }
      const float acc = (a0 + a1) + (a2 + a3);
      __hip_bfloat16 hb = __float2bfloat16(acc);
      h_s[n0 + r][lane] = *(unsigned short*)&hb;
    }
  }
  __syncthreads();

  // ---------- Phase 2a: per-node attention logits (thread n) ----------
  for (int n = tid; n < N_; n += BLK) {
    const unsigned* hr = (const unsigned*)&h_s[n][0];
    const float2* at2 = (const float2*)atts_s;
    const float2* ad2 = (const float2*)attd_s;
    float as = 0.f, ad = 0.f;
#pragma unroll
    for (int i = 0; i < 32; ++i) {
      unsigned hp = hr[i];
      float h0 = bflo(hp), h1 = bfhi(hp);
      float2 s2 = at2[i], d2 = ad2[i];
      as += h0 * s2.x + h1 * s2.y;
      ad += h0 * d2.x + h1 * d2.y;
    }
    as_s[n] = as; ad_s[n] = ad;
  }
  __syncthreads();

  // ---------- Phase 2b: per-dst segment softmax (thread n) ----------
  for (int n = tid; n < N_; n += BLK) {
    const int beg = coff_s[n], end = coff_s[n + 1];
    const float adn = ad_s[n];
    float mx = -1e30f;
    for (int p = beg; p < end; ++p) {
      float e = as_s[csrc_s[p]] + adn;
      e = fmaxf(e, 0.2f * e);                 // leaky_relu
      alpha_s[p] = e;
      mx = fmaxf(mx, e);
    }
    float den = 0.f;
    for (int p = beg; p < end; ++p) {
      float ex = __expf(alpha_s[p] - mx);
      alpha_s[p] = ex;                        // unnormalized
      den += ex;
    }
    den_s[n] = (end > beg) ? den : 1.0f;
  }
  __syncthreads();

  // ---------- Phase 3: aggregation + GELU (wave per dst, 2 edges/iter, full-wave store) ----------
  const int k    = lane & 31;                 // channel pair index
  const int half = lane >> 5;                 // which edge of the pair
  const float bias_r = bias[lane];
  for (int n = wv; n < N_; n += 8) {
    const int beg = coff_s[n], end = coff_s[n + 1];
    float ax = 0.f, ay = 0.f;
    for (int p = beg; p < end; p += 2) {
      const int idx = p + half;
      const int ic  = (idx < end) ? idx : p;  // clamp (p < end guaranteed)
      float a = alpha_s[ic];
      a = (idx < end) ? a : 0.f;
      const int s = csrc_s[ic];
      unsigned hp = *(const unsigned*)&h_s[s][2 * k];
      ax += a * bflo(hp);
      ay += a * bfhi(hp);
    }
    ax += __shfl_xor(ax, 32, 64);
    ay += __shfl_xor(ay, 32, 64);
    // redistribute: lane c takes channel c from pair holder lane c>>1
    float vx = __shfl(ax, lane >> 1, 64);
    float vy = __shfl(ay, lane >> 1, 64);
    float v = (lane & 1) ? vy : vx;
    v = v * (1.0f / den_s[n]) + bias_r;
    v = 0.5f * v * (1.f + erff(v * 0.70710678118f));
    out[((size_t)g * N_ + n) * H_ + lane] = v;  // full-wave 256B coalesced store
  }
}

extern "C" void kernel_launch(void* const* d_in, const int* in_sizes, int n_in,
                              void* d_out, int out_size, void* d_ws, size_t ws_size,
                              hipStream_t stream) {
  (void)in_sizes; (void)n_in; (void)out_size; (void)ws_size;
  const float* x       = (const float*)d_in[0];
  const int*   ei      = (const int*)d_in[1];
  const float* W       = (const float*)d_in[2];
  const float* att_src = (const float*)d_in[3];
  const float* att_dst = (const float*)d_in[4];
  const float* bias    = (const float*)d_in[5];
  float* out = (float*)d_out;
  int* csr_off = (int*)d_ws;              // N_+1 ints
  int* csr_src = csr_off + (N_ + 1);      // E_ ints

  k_offsets<<<1, BLK, 0, stream>>>(ei, csr_off);
  k_scatter<<<(E_ + 63) / 64, 64, 0, stream>>>(ei, csr_off, csr_src);
  k_gat<<<G_, BLK, 0, stream>>>(x, csr_off, csr_src, W, att_src, att_dst, bias, out);
}

// Round 4
// 155.642 us; speedup vs baseline: 6.5854x; 1.7964x over previous
//
#include <hip/hip_runtime.h>
#include <hip/hip_bf16.h>

#define B_  64
#define N_  325
#define T_  24
#define F_  64
#define H_  64
#define E_  2600
#define G_  (B_ * T_)
#define BLK 512
#define HS  66   // h_s row stride in bf16 units (132 B -> +1 bank/row, conflict-free)

typedef __attribute__((ext_vector_type(8))) short short8;   // 8 bf16 (4 VGPRs)
typedef __attribute__((ext_vector_type(4))) float f32x4;

// ---------------- K0a: per-dst counts -> exclusive offsets ----------------
__global__ __launch_bounds__(512) void k_offsets(const int* __restrict__ ei,
                                                 int* __restrict__ csr_off) {
  __shared__ int cnt[N_];
  const int tid = threadIdx.x;
  for (int i = tid; i < N_; i += BLK) cnt[i] = 0;
  __syncthreads();
  for (int e = tid; e < E_; e += BLK) atomicAdd(&cnt[ei[E_ + e]], 1);
  __syncthreads();
  if (tid <= N_) {
    int off = 0;
    for (int m = 0; m < N_; ++m) off += (m < tid) ? cnt[m] : 0;  // uniform m -> LDS broadcast
    csr_off[tid] = off;
  }
}

// ---------------- K0b: stable scatter of src ids by dst (deterministic) ----------------
__global__ __launch_bounds__(64) void k_scatter(const int* __restrict__ ei,
                                                const int* __restrict__ csr_off,
                                                int* __restrict__ csr_src) {
  __shared__ int dsts[E_];
  const int tid = threadIdx.x;
  for (int i = tid; i < E_; i += 64) dsts[i] = ei[E_ + i];
  __syncthreads();
  const int e = blockIdx.x * 64 + tid;
  if (e >= E_) return;
  const int myd = dsts[e];
  int rank = 0;
#pragma unroll 4
  for (int k = 0; k < e; ++k) rank += (dsts[k] == myd) ? 1 : 0;
  csr_src[csr_off[myd] + rank] = ei[e];  // src id, stable original-edge order
}

__device__ __forceinline__ float bflo(unsigned u) { return __uint_as_float(u << 16); }
__device__ __forceinline__ float bfhi(unsigned u) { return __uint_as_float(u & 0xffff0000u); }

__device__ __forceinline__ unsigned short f2bf(float f) {
  __hip_bfloat16 h = __float2bfloat16(f);
  return *(unsigned short*)&h;
}

// load 8 consecutive f32 and convert to a bf16x8 fragment
__device__ __forceinline__ short8 ld8_bf16(const float* p) {
  float4 u = *(const float4*)p;
  float4 w = *(const float4*)(p + 4);
  short8 r;
  r[0] = (short)f2bf(u.x); r[1] = (short)f2bf(u.y);
  r[2] = (short)f2bf(u.z); r[3] = (short)f2bf(u.w);
  r[4] = (short)f2bf(w.x); r[5] = (short)f2bf(w.y);
  r[6] = (short)f2bf(w.z); r[7] = (short)f2bf(w.w);
  return r;
}

// exact-ish GELU via tanh form: v * e / (e+1), e = exp(2*0.79788456*(v+0.044715 v^3))
__device__ __forceinline__ float gelu_f(float v) {
  float t = v * (1.5957691216f + 0.0713550903f * (v * v));
  t = fminf(t, 80.0f);
  float e = __expf(t);
  return v * e * __builtin_amdgcn_rcpf(e + 1.0f);
}

// ---------------- main fused kernel: one block per graph, 2 blocks/CU ----------------
__global__ __launch_bounds__(512, 4) void k_gat(
    const float* __restrict__ x, const int* __restrict__ csr_off_g,
    const int* __restrict__ csr_src_g, const float* __restrict__ W,
    const float* __restrict__ att_src, const float* __restrict__ att_dst,
    const float* __restrict__ bias, float* __restrict__ out) {
  __shared__ unsigned short h_s[N_][HS];            // 42900 B, bf16
  __shared__ float alpha_s[E_];                     // 10400 B (unnormalized exp)
  __shared__ unsigned short csrc_s[E_];             //  5200 B (src ids < 325)
  __shared__ int   coff_s[N_ + 1];                  //  1304 B
  __shared__ float as_s[N_], ad_s[N_], den_s[N_];   //  3900 B (den_s holds 1/den)
  __shared__ __align__(8) float atts_s[H_], attd_s[H_];  // 512 B   total ~62.7 KB

  const int g    = blockIdx.x;      // graph id = b*T + t
  const int bb   = g / T_;
  const int tt   = g % T_;
  const int tid  = threadIdx.x;
  const int lane = tid & 63;
  const int wv   = tid >> 6;        // wave 0..7
  const int l15  = lane & 15;
  const int l4   = lane >> 4;       // 0..3

  // stage CSR + att vectors
  for (int i = tid; i < E_; i += BLK) csrc_s[i] = (unsigned short)csr_src_g[i];
  for (int i = tid; i <= N_; i += BLK) coff_s[i] = csr_off_g[i];
  if (tid < H_) { atts_s[tid] = att_src[tid]; attd_s[tid] = att_dst[tid]; }

  // ---------- Phase 1: h = x @ W^T via MFMA 16x16x32 bf16 ----------
  // B fragment: B[k][c] = W^T[k][c0+c] = W[c0+(l&15)][k], k = k0*32 + (l>>4)*8 + j
  short8 bf[2][4];
#pragma unroll
  for (int ct = 0; ct < 4; ++ct) {
#pragma unroll
    for (int k0 = 0; k0 < 2; ++k0)
      bf[k0][ct] = ld8_bf16(W + (size_t)(ct * 16 + l15) * F_ + k0 * 32 + l4 * 8);
  }

  const float* xg = x + ((size_t)bb * N_ * T_ + tt) * F_;
  // 21 row-tiles of 16 (last partial: rows 320..324), wave t owns tiles t, t+8, ...
  for (int t = wv; t < 21; t += 8) {
    const int r0 = t * 16;
    int rr = r0 + l15; if (rr > N_ - 1) rr = N_ - 1;      // clamp (avoid OOB)
    const float* xr = xg + (size_t)rr * (T_ * F_);
    const short8 a0 = ld8_bf16(xr + l4 * 8);              // k 0..31
    const short8 a1 = ld8_bf16(xr + 32 + l4 * 8);         // k 32..63
#pragma unroll
    for (int ct = 0; ct < 4; ++ct) {
      f32x4 acc = {0.f, 0.f, 0.f, 0.f};
      acc = __builtin_amdgcn_mfma_f32_16x16x32_bf16(a0, bf[0][ct], acc, 0, 0, 0);
      acc = __builtin_amdgcn_mfma_f32_16x16x32_bf16(a1, bf[1][ct], acc, 0, 0, 0);
      const int col = ct * 16 + l15;                      // C: col = lane&15
#pragma unroll
      for (int j = 0; j < 4; ++j) {                       // C: row = (lane>>4)*4 + j
        const int row = r0 + l4 * 4 + j;
        if (row < N_) h_s[row][col] = f2bf(acc[j]);
      }
    }
  }
  __syncthreads();

  // ---------- Phase 2a: per-node attention logits (thread n) ----------
  for (int n = tid; n < N_; n += BLK) {
    const unsigned* hr = (const unsigned*)&h_s[n][0];
    const float2* at2 = (const float2*)atts_s;
    const float2* ad2 = (const float2*)attd_s;
    float as = 0.f, ad = 0.f;
#pragma unroll
    for (int i = 0; i < 32; ++i) {
      unsigned hp = hr[i];
      float h0 = bflo(hp), h1 = bfhi(hp);
      float2 s2 = at2[i], d2 = ad2[i];
      as += h0 * s2.x + h1 * s2.y;
      ad += h0 * d2.x + h1 * d2.y;
    }
    as_s[n] = as; ad_s[n] = ad;
  }
  __syncthreads();

  // ---------- Phase 2b: per-dst segment softmax (thread n), den_s = 1/den ----------
  for (int n = tid; n < N_; n += BLK) {
    const int beg = coff_s[n], end = coff_s[n + 1];
    const float adn = ad_s[n];
    float mx = -1e30f;
    for (int p = beg; p < end; ++p) {
      float e = as_s[csrc_s[p]] + adn;
      e = fmaxf(e, 0.2f * e);                 // leaky_relu
      alpha_s[p] = e;
      mx = fmaxf(mx, e);
    }
    float den = 0.f;
    for (int p = beg; p < end; ++p) {
      float ex = __expf(alpha_s[p] - mx);
      alpha_s[p] = ex;                        // unnormalized
      den += ex;
    }
    den_s[n] = (end > beg) ? (1.0f / den) : 1.0f;
  }
  __syncthreads();

  // ---------- Phase 3: aggregation + GELU (half-wave per dst, no shuffles) ----------
  const int k   = lane & 31;                  // channel pair (covers H=64 as 32 pairs)
  const int sub = lane >> 5;                  // which dst of the wave's pair
  const float2 bias2 = *(const float2*)(bias + 2 * k);
  for (int n = wv * 2 + sub; n < N_; n += 16) {
    const int beg = coff_s[n], end = coff_s[n + 1];
    float ax = 0.f, ay = 0.f;
    for (int p = beg; p < end; ++p) {
      const float a = alpha_s[p];             // broadcast within half-wave
      const int   s = csrc_s[p];
      unsigned hp = *(const unsigned*)&h_s[s][2 * k];  // 32 consecutive dwords
      ax += a * bflo(hp);
      ay += a * bfhi(hp);
    }
    const float r = den_s[n];                 // 1/den
    float v0 = ax * r + bias2.x;
    float v1 = ay * r + bias2.y;
    v0 = gelu_f(v0);
    v1 = gelu_f(v1);
    *(float2*)&out[((size_t)g * N_ + n) * H_ + 2 * k] = make_float2(v0, v1);
  }
}

extern "C" void kernel_launch(void* const* d_in, const int* in_sizes, int n_in,
                              void* d_out, int out_size, void* d_ws, size_t ws_size,
                              hipStream_t stream) {
  (void)in_sizes; (void)n_in; (void)out_size; (void)ws_size;
  const float* x       = (const float*)d_in[0];
  const int*   ei      = (const int*)d_in[1];
  const float* W       = (const float*)d_in[2];
  const float* att_src = (const float*)d_in[3];
  const float* att_dst = (const float*)d_in[4];
  const float* bias    = (const float*)d_in[5];
  float* out = (float*)d_out;
  int* csr_off = (int*)d_ws;              // N_+1 ints
  int* csr_src = csr_off + (N_ + 1);      // E_ ints

  k_offsets<<<1, BLK, 0, stream>>>(ei, csr_off);
  k_scatter<<<(E_ + 63) / 64, 64, 0, stream>>>(ei, csr_off, csr_src);
  k_gat<<<G_, BLK, 0, stream>>>(x, csr_off, csr_src, W, att_src, att_dst, bias, out);
}